// Round 4
// baseline (531.166 us; speedup 1.0000x reference)
//
#include <hip/hip_runtime.h>
#include <math.h>

// ARAP projection, 8 Adam steps, fused into ONE persistent kernel using a
// hand-rolled sense-reversing grid barrier (regular launch; cooperative
// launch API failed in this harness in R3). 196 blocks x 512 threads <=
// 256 CUs with __launch_bounds__(512,2) -> all blocks co-resident.
// Per-edge invariants (nbr, w, w*(xi-xj)), Adam m/v, and own recon live in
// registers across all 8 steps. A tiny init kernel resets barrier state
// every call (ws is poisoned once and never re-poisoned by the harness).

#define BLK 512
#define MAXK 8
#define NSTEP 8

__global__ void bar_init(int* __restrict__ bar) {
    bar[0] = 0;   // arrive count
    bar[1] = 0;   // sense
}

__device__ __forceinline__ void grid_barrier(int* __restrict__ bar, int nblocks,
                                             int& localSense) {
    __syncthreads();
    if (threadIdx.x == 0) {
        int my = localSense ^ 1;
        localSense = my;
        int prev = __hip_atomic_fetch_add(&bar[0], 1, __ATOMIC_ACQ_REL,
                                          __HIP_MEMORY_SCOPE_AGENT);
        if (prev == nblocks - 1) {
            // last arriver: reset count, then release the flipped sense
            __hip_atomic_store(&bar[0], 0, __ATOMIC_RELAXED,
                               __HIP_MEMORY_SCOPE_AGENT);
            __hip_atomic_store(&bar[1], my, __ATOMIC_RELEASE,
                               __HIP_MEMORY_SCOPE_AGENT);
        } else {
            while (__hip_atomic_load(&bar[1], __ATOMIC_ACQUIRE,
                                     __HIP_MEMORY_SCOPE_AGENT) != my) {
                __builtin_amdgcn_s_sleep(2);
            }
        }
    }
    __syncthreads();
}

__global__ void __launch_bounds__(BLK, 2) arap_persist(
    const float* __restrict__ xyz, const float* __restrict__ recon0,
    const int* __restrict__ nbr, const int* __restrict__ num,
    const int* __restrict__ acc, const float* __restrict__ wm,
    const float* __restrict__ arapW,
    int* __restrict__ bar,
    float4* __restrict__ Rpad,            // n*4 float4 (3 rows + pad, 64B/vtx)
    float4* __restrict__ rbufA,           // n float4 recon ping
    float4* __restrict__ rbufB,           // n float4 recon pong
    float* __restrict__ out, int n)
{
    int nblocks = gridDim.x;
    int localSense = 0;
    int i = blockIdx.x * blockDim.x + threadIdx.x;
    bool active = (i < n);

    int   jn[MAXK];
    float w[MAXK];
    float we0[MAXK], we1[MAXK], we2[MAXK];   // w * (xi - xj)
    float pj0[MAXK], pj1[MAXK], pj2[MAXK];   // neighbor recon cache (per step)
    float pi0 = 0.f, pi1 = 0.f, pi2 = 0.f;
    float m0 = 0.f, m1 = 0.f, m2 = 0.f, v0 = 0.f, v1 = 0.f, v2 = 0.f;
    float aw = 0.f;

    if (active) {
        aw = arapW[0];
        int e0 = acc[i];
        int cnt = num[i]; if (cnt > MAXK) cnt = MAXK;
        float xi0 = xyz[3*i+0], xi1 = xyz[3*i+1], xi2 = xyz[3*i+2];
        pi0 = recon0[3*i+0]; pi1 = recon0[3*i+1]; pi2 = recon0[3*i+2];
#pragma unroll
        for (int e = 0; e < MAXK; ++e) {
            int jj; float wv;
            if (e < cnt) { jj = nbr[e0+e]; wv = wm[e0+e]; }
            else         { jj = i;         wv = 0.f;      }   // zero-weight pad
            jn[e] = jj; w[e] = wv;
            we0[e] = wv * (xi0 - xyz[3*jj+0]);
            we1[e] = wv * (xi1 - xyz[3*jj+1]);
            we2[e] = wv * (xi2 - xyz[3*jj+2]);
        }
        rbufA[i] = make_float4(pi0, pi1, pi2, 0.f);
    }
    grid_barrier(bar, nblocks, localSense);

    const float4* rc = rbufA;
    float4*       rn = rbufB;

    float b1p = 1.f, b2p = 1.f;

    for (int step = 1; step <= NSTEP; ++step) {
        b1p *= 0.9f;
        b2p *= 0.999f;

        float A00=0,A01=0,A02=0,A10=0,A11=0,A12=0,A20=0,A21=0,A22=0;

        if (active) {
            // ---- gather neighbor recon once (reused in grad phase) ----
#pragma unroll
            for (int e = 0; e < MAXK; ++e) {
                float4 p = rc[jn[e]];
                pj0[e] = p.x; pj1[e] = p.y; pj2[e] = p.z;
            }

            // ---- S = sum w*(xi-xj) (pi-pj)^T ----
            float S00=0,S01=0,S02=0,S10=0,S11=0,S12=0,S20=0,S21=0,S22=0;
#pragma unroll
            for (int e = 0; e < MAXK; ++e) {
                float ed0 = pi0 - pj0[e], ed1 = pi1 - pj1[e], ed2 = pi2 - pj2[e];
                S00 += we0[e]*ed0; S01 += we0[e]*ed1; S02 += we0[e]*ed2;
                S10 += we1[e]*ed0; S11 += we1[e]*ed1; S12 += we1[e]*ed2;
                S20 += we2[e]*ed0; S21 += we2[e]*ed1; S22 += we2[e]*ed2;
            }

            float detS = S00*(S11*S22 - S12*S21)
                       - S01*(S10*S22 - S12*S20)
                       + S02*(S10*S21 - S11*S20);

            // A = S^T ; scaled Newton polar -> Q = V U^T, det(Q)=sign(det S)
            A00 = S00; A01 = S10; A02 = S20;
            A10 = S01; A11 = S11; A12 = S21;
            A20 = S02; A21 = S12; A22 = S22;

            float fS = A00*A00+A01*A01+A02*A02+A10*A10+A11*A11+A12*A12
                     + A20*A20+A21*A21+A22*A22;
            if (fS < 1e-24f) {
                A00=1.f; A01=0.f; A02=0.f;
                A10=0.f; A11=1.f; A12=0.f;
                A20=0.f; A21=0.f; A22=1.f;
            } else {
#pragma unroll
                for (int it = 0; it < 10; ++it) {
                    float C00 = A11*A22 - A12*A21;
                    float C01 = A12*A20 - A10*A22;
                    float C02 = A10*A21 - A11*A20;
                    float C10 = A02*A21 - A01*A22;
                    float C11 = A00*A22 - A02*A20;
                    float C12 = A01*A20 - A00*A21;
                    float C20 = A01*A12 - A02*A11;
                    float C21 = A02*A10 - A00*A12;
                    float C22 = A00*A11 - A01*A10;
                    float det = A00*C00 + A01*C01 + A02*C02;
                    float ad = fmaxf(fabsf(det), 1e-30f);
                    det = (det < 0.f) ? -ad : ad;
                    float fA = A00*A00+A01*A01+A02*A02+A10*A10+A11*A11
                             + A12*A12+A20*A20+A21*A21+A22*A22;
                    float fC = C00*C00+C01*C01+C02*C02+C10*C10+C11*C11
                             + C12*C12+C20*C20+C21*C21+C22*C22;
                    float g = sqrtf(sqrtf(fC / fmaxf(ad*ad*fA, 1e-38f)));
                    float s0 = 0.5f * g;
                    float s1 = 0.5f / (g * det);
                    A00 = s0*A00 + s1*C00; A01 = s0*A01 + s1*C01; A02 = s0*A02 + s1*C02;
                    A10 = s0*A10 + s1*C10; A11 = s0*A11 + s1*C11; A12 = s0*A12 + s1*C12;
                    A20 = s0*A20 + s1*C20; A21 = s0*A21 + s1*C21; A22 = s0*A22 + s1*C22;
                }

                if (detS < 0.f) {
                    // R = Q (I - 2 u3 u3^T), u3 = min-eigvec of H = Q^T S^T
                    float H00 = A00*S00 + A10*S01 + A20*S02;
                    float H01 = A00*S10 + A10*S11 + A20*S12;
                    float H02 = A00*S20 + A10*S21 + A20*S22;
                    float H10 = A01*S00 + A11*S01 + A21*S02;
                    float H11 = A01*S10 + A11*S11 + A21*S12;
                    float H12 = A01*S20 + A11*S21 + A21*S22;
                    float H20 = A02*S00 + A12*S01 + A22*S02;
                    float H21 = A02*S10 + A12*S11 + A22*S12;
                    float H22 = A02*S20 + A12*S21 + A22*S22;
                    float h01 = 0.5f*(H01 + H10);
                    float h02 = 0.5f*(H02 + H20);
                    float h12 = 0.5f*(H12 + H21);

                    float q  = (H00 + H11 + H22) * (1.f/3.f);
                    float p1 = h01*h01 + h02*h02 + h12*h12;
                    float a00 = H00 - q, a11 = H11 - q, a22 = H22 - q;
                    float p2 = a00*a00 + a11*a11 + a22*a22 + 2.f*p1;
                    float p  = sqrtf(fmaxf(p2 * (1.f/6.f), 1e-30f));
                    float ip = 1.f / p;
                    float b00 = a00*ip, b01 = h01*ip, b02 = h02*ip;
                    float b11 = a11*ip, b12 = h12*ip, b22 = a22*ip;
                    float detB = b00*(b11*b22 - b12*b12)
                               - b01*(b01*b22 - b12*b02)
                               + b02*(b01*b12 - b11*b02);
                    float r   = fminf(1.f, fmaxf(-1.f, 0.5f*detB));
                    float phi = acosf(r) * (1.f/3.f);
                    float l1 = q + 2.f*p*cosf(phi);
                    float l3 = q + 2.f*p*cosf(phi + 2.0943951023931953f);
                    float l2 = 3.f*q - l1 - l3;

                    float m100 = H00-l1, m111 = H11-l1, m122 = H22-l1;
                    float m200 = H00-l2, m211 = H11-l2, m222 = H22-l2;
                    float P00 = m100*m200 + h01*h01 + h02*h02;
                    float P10 = h01*m200 + m111*h01 + h12*h02;
                    float P20 = h02*m200 + h12*h01 + m122*h02;
                    float P01 = m100*h01 + h01*m211 + h02*h12;
                    float P11 = h01*h01 + m111*m211 + h12*h12;
                    float P21 = h02*h01 + h12*m211 + m122*h12;
                    float P02 = m100*h02 + h01*h12 + h02*m222;
                    float P12 = h01*h02 + m111*h12 + h12*m222;
                    float P22 = h02*h02 + h12*h12 + m122*m222;

                    float n0 = P00*P00 + P10*P10 + P20*P20;
                    float n1 = P01*P01 + P11*P11 + P21*P21;
                    float n2 = P02*P02 + P12*P12 + P22*P22;
                    float u0, u1, u2, nn;
                    if (n0 >= n1 && n0 >= n2) { u0=P00; u1=P10; u2=P20; nn=n0; }
                    else if (n1 >= n2)        { u0=P01; u1=P11; u2=P21; nn=n1; }
                    else                      { u0=P02; u1=P12; u2=P22; nn=n2; }
                    if (nn > 1e-30f) {
                        float inv = rsqrtf(nn);
                        u0 *= inv; u1 *= inv; u2 *= inv;
                        float Qu0 = A00*u0 + A01*u1 + A02*u2;
                        float Qu1 = A10*u0 + A11*u1 + A12*u2;
                        float Qu2 = A20*u0 + A21*u1 + A22*u2;
                        A00 -= 2.f*Qu0*u0; A01 -= 2.f*Qu0*u1; A02 -= 2.f*Qu0*u2;
                        A10 -= 2.f*Qu1*u0; A11 -= 2.f*Qu1*u1; A12 -= 2.f*Qu1*u2;
                        A20 -= 2.f*Qu2*u0; A21 -= 2.f*Qu2*u1; A22 -= 2.f*Qu2*u2;
                    }
                }
            }

            size_t ib = 4*(size_t)i;
            Rpad[ib+0] = make_float4(A00, A01, A02, 0.f);
            Rpad[ib+1] = make_float4(A10, A11, A12, 0.f);
            Rpad[ib+2] = make_float4(A20, A21, A22, 0.f);
        }

        grid_barrier(bar, nblocks, localSense);   // all R visible

        if (active) {
            float g0 = 0.f, g1 = 0.f, g2 = 0.f;
#pragma unroll
            for (int e = 0; e < MAXK; ++e) {
                size_t jb = 4*(size_t)jn[e];
                float4 r0 = Rpad[jb+0];
                float4 r1 = Rpad[jb+1];
                float4 r2 = Rpad[jb+2];
                float ed0 = pi0 - pj0[e], ed1 = pi1 - pj1[e], ed2 = pi2 - pj2[e];
                float tw = 2.f * w[e];
                g0 += tw*ed0 - ((A00+r0.x)*we0[e] + (A01+r0.y)*we1[e] + (A02+r0.z)*we2[e]);
                g1 += tw*ed1 - ((A10+r1.x)*we0[e] + (A11+r1.y)*we1[e] + (A12+r1.z)*we2[e]);
                g2 += tw*ed2 - ((A20+r2.x)*we0[e] + (A21+r2.y)*we1[e] + (A22+r2.z)*we2[e]);
            }
            g0 *= aw; g1 *= aw; g2 *= aw;

            m0 = 0.9f*m0 + 0.1f*g0;
            m1 = 0.9f*m1 + 0.1f*g1;
            m2 = 0.9f*m2 + 0.1f*g2;
            v0 = 0.999f*v0 + 0.001f*g0*g0;
            v1 = 0.999f*v1 + 0.001f*g1*g1;
            v2 = 0.999f*v2 + 0.001f*g2*g2;

            float ib1 = 1.f / (1.f - b1p);
            float ib2 = 1.f / (1.f - b2p);
            const float RATE = 0.01f, EPS = 1e-9f;
            pi0 -= RATE * ((m0*ib1) / (sqrtf(v0*ib2) + EPS));
            pi1 -= RATE * ((m1*ib1) / (sqrtf(v1*ib2) + EPS));
            pi2 -= RATE * ((m2*ib1) / (sqrtf(v2*ib2) + EPS));

            if (step < NSTEP) {
                rn[i] = make_float4(pi0, pi1, pi2, 0.f);
            } else {
                out[3*(size_t)i+0] = pi0;
                out[3*(size_t)i+1] = pi1;
                out[3*(size_t)i+2] = pi2;
            }
        }

        if (step < NSTEP) {
            grid_barrier(bar, nblocks, localSense);   // next recon visible
            const float4* t = rc; rc = rn; rn = (float4*)t;
        }
    }
}

extern "C" void kernel_launch(void* const* d_in, const int* in_sizes, int n_in,
                              void* d_out, int out_size, void* d_ws, size_t ws_size,
                              hipStream_t stream) {
    const float* xyz    = (const float*)d_in[0];
    const float* recon0 = (const float*)d_in[1];
    const int*   nbr    = (const int*)d_in[2];
    const int*   num    = (const int*)d_in[3];
    const int*   acc    = (const int*)d_in[4];
    const float* wm     = (const float*)d_in[5];
    const float* aw     = (const float*)d_in[6];

    int n = in_sizes[0] / 3;
    float* out = (float*)d_out;

    int*    bar   = (int*)d_ws;                              // 2 ints (pad 256B)
    float4* Rpad  = (float4*)((char*)d_ws + 256);            // n*4 float4
    float4* rbufA = Rpad  + 4*(size_t)n;                     // n float4
    float4* rbufB = rbufA + (size_t)n;                       // n float4

    int grid = (n + BLK - 1) / BLK;   // 196 for n=100000 (<= 256 CUs)

    bar_init<<<1, 1, 0, stream>>>(bar);
    arap_persist<<<grid, BLK, 0, stream>>>(xyz, recon0, nbr, num, acc, wm, aw,
                                           bar, Rpad, rbufA, rbufB, out, n);
}

// Round 5
// 472.896 us; speedup vs baseline: 1.1232x; 1.1232x over previous
//
#include <hip/hip_runtime.h>
#include <math.h>

// ARAP projection, 8 Adam steps. Multi-dispatch (persistent version regressed:
// occupancy capped at 19%, 300MB L2-miss traffic). Structure: 1 prep + 8x(rot,
// grad) dispatches. Each step kernel uses 8 LANES PER VERTEX (one per edge) for
// 8x memory-level parallelism; cross-lane reduction via __shfl_xor within the
// aligned 8-lane group. Rotations stored as UNIT QUATERNIONS (16B gather, not
// 48B) so the per-step gather hot-set (xyz4+recon4+quat = 4.8MB) ~ fits XCD L2.

#define BLK 256
#define MAXK 8
#define NSTEP 8

__global__ void prep_kernel(const float* __restrict__ xyz,
                            const float* __restrict__ recon0,
                            float4* __restrict__ xyz4,
                            float4* __restrict__ rbufA, int n) {
    int i = blockIdx.x * blockDim.x + threadIdx.x;
    if (i < n) {
        xyz4[i]  = make_float4(xyz[3*i], xyz[3*i+1], xyz[3*i+2], 0.f);
        rbufA[i] = make_float4(recon0[3*i], recon0[3*i+1], recon0[3*i+2], 0.f);
    }
}

// polar decomposition of S^T via scaled Newton + det<0 reflection fix,
// returned as quaternion (x,y,z,w). Matches SVD ref: R = V U^T (det-corrected).
__device__ float4 polar_quat(float S00, float S01, float S02,
                             float S10, float S11, float S12,
                             float S20, float S21, float S22) {
    float detS = S00*(S11*S22 - S12*S21)
               - S01*(S10*S22 - S12*S20)
               + S02*(S10*S21 - S11*S20);

    float A00 = S00, A01 = S10, A02 = S20;
    float A10 = S01, A11 = S11, A12 = S21;
    float A20 = S02, A21 = S12, A22 = S22;

    float fS = A00*A00+A01*A01+A02*A02+A10*A10+A11*A11+A12*A12
             + A20*A20+A21*A21+A22*A22;
    if (fS < 1e-24f) {
        A00=1.f; A01=0.f; A02=0.f;
        A10=0.f; A11=1.f; A12=0.f;
        A20=0.f; A21=0.f; A22=1.f;
    } else {
#pragma unroll
        for (int it = 0; it < 10; ++it) {
            float C00 = A11*A22 - A12*A21;
            float C01 = A12*A20 - A10*A22;
            float C02 = A10*A21 - A11*A20;
            float C10 = A02*A21 - A01*A22;
            float C11 = A00*A22 - A02*A20;
            float C12 = A01*A20 - A00*A21;
            float C20 = A01*A12 - A02*A11;
            float C21 = A02*A10 - A00*A12;
            float C22 = A00*A11 - A01*A10;
            float det = A00*C00 + A01*C01 + A02*C02;
            float ad = fmaxf(fabsf(det), 1e-30f);
            det = (det < 0.f) ? -ad : ad;
            float fA = A00*A00+A01*A01+A02*A02+A10*A10+A11*A11
                     + A12*A12+A20*A20+A21*A21+A22*A22;
            float fC = C00*C00+C01*C01+C02*C02+C10*C10+C11*C11
                     + C12*C12+C20*C20+C21*C21+C22*C22;
            float g = sqrtf(sqrtf(fC / fmaxf(ad*ad*fA, 1e-38f)));
            float s0 = 0.5f * g;
            float s1 = 0.5f / (g * det);
            A00 = s0*A00 + s1*C00; A01 = s0*A01 + s1*C01; A02 = s0*A02 + s1*C02;
            A10 = s0*A10 + s1*C10; A11 = s0*A11 + s1*C11; A12 = s0*A12 + s1*C12;
            A20 = s0*A20 + s1*C20; A21 = s0*A21 + s1*C21; A22 = s0*A22 + s1*C22;
        }

        if (detS < 0.f) {
            float H00 = A00*S00 + A10*S01 + A20*S02;
            float H01 = A00*S10 + A10*S11 + A20*S12;
            float H02 = A00*S20 + A10*S21 + A20*S22;
            float H10 = A01*S00 + A11*S01 + A21*S02;
            float H11 = A01*S10 + A11*S11 + A21*S12;
            float H12 = A01*S20 + A11*S21 + A21*S22;
            float H20 = A02*S00 + A12*S01 + A22*S02;
            float H21 = A02*S10 + A12*S11 + A22*S12;
            float H22 = A02*S20 + A12*S21 + A22*S22;
            float h01 = 0.5f*(H01 + H10);
            float h02 = 0.5f*(H02 + H20);
            float h12 = 0.5f*(H12 + H21);

            float q  = (H00 + H11 + H22) * (1.f/3.f);
            float p1 = h01*h01 + h02*h02 + h12*h12;
            float a00 = H00 - q, a11 = H11 - q, a22 = H22 - q;
            float p2 = a00*a00 + a11*a11 + a22*a22 + 2.f*p1;
            float p  = sqrtf(fmaxf(p2 * (1.f/6.f), 1e-30f));
            float ip = 1.f / p;
            float b00 = a00*ip, b01 = h01*ip, b02 = h02*ip;
            float b11 = a11*ip, b12 = h12*ip, b22 = a22*ip;
            float detB = b00*(b11*b22 - b12*b12)
                       - b01*(b01*b22 - b12*b02)
                       + b02*(b01*b12 - b11*b02);
            float r   = fminf(1.f, fmaxf(-1.f, 0.5f*detB));
            float phi = acosf(r) * (1.f/3.f);
            float l1 = q + 2.f*p*cosf(phi);
            float l2v = q + 2.f*p*cosf(phi + 2.0943951023931953f); // actually l3
            float l3 = l2v;
            float l2 = 3.f*q - l1 - l3;

            float m100 = H00-l1, m111 = H11-l1, m122 = H22-l1;
            float m200 = H00-l2, m211 = H11-l2, m222 = H22-l2;
            float P00 = m100*m200 + h01*h01 + h02*h02;
            float P10 = h01*m200 + m111*h01 + h12*h02;
            float P20 = h02*m200 + h12*h01 + m122*h02;
            float P01 = m100*h01 + h01*m211 + h02*h12;
            float P11 = h01*h01 + m111*m211 + h12*h12;
            float P21 = h02*h01 + h12*m211 + m122*h12;
            float P02 = m100*h02 + h01*h12 + h02*m222;
            float P12 = h01*h02 + m111*h12 + h12*m222;
            float P22 = h02*h02 + h12*h12 + m122*m222;

            float n0 = P00*P00 + P10*P10 + P20*P20;
            float n1 = P01*P01 + P11*P11 + P21*P21;
            float n2 = P02*P02 + P12*P12 + P22*P22;
            float u0, u1, u2, nn;
            if (n0 >= n1 && n0 >= n2) { u0=P00; u1=P10; u2=P20; nn=n0; }
            else if (n1 >= n2)        { u0=P01; u1=P11; u2=P21; nn=n1; }
            else                      { u0=P02; u1=P12; u2=P22; nn=n2; }
            if (nn > 1e-30f) {
                float inv = rsqrtf(nn);
                u0 *= inv; u1 *= inv; u2 *= inv;
                float Qu0 = A00*u0 + A01*u1 + A02*u2;
                float Qu1 = A10*u0 + A11*u1 + A12*u2;
                float Qu2 = A20*u0 + A21*u1 + A22*u2;
                A00 -= 2.f*Qu0*u0; A01 -= 2.f*Qu0*u1; A02 -= 2.f*Qu0*u2;
                A10 -= 2.f*Qu1*u0; A11 -= 2.f*Qu1*u1; A12 -= 2.f*Qu1*u2;
                A20 -= 2.f*Qu2*u0; A21 -= 2.f*Qu2*u1; A22 -= 2.f*Qu2*u2;
            }
        }
    }

    // rotation matrix -> quaternion (Shepperd)
    float qw, qx, qy, qz;
    float tr = A00 + A11 + A22;
    if (tr > 0.f) {
        float s = sqrtf(tr + 1.f) * 2.f;
        qw = 0.25f*s; float is = 1.f/s;
        qx = (A21 - A12)*is; qy = (A02 - A20)*is; qz = (A10 - A01)*is;
    } else if (A00 > A11 && A00 > A22) {
        float s = sqrtf(1.f + A00 - A11 - A22) * 2.f;
        qx = 0.25f*s; float is = 1.f/s;
        qw = (A21 - A12)*is; qy = (A01 + A10)*is; qz = (A02 + A20)*is;
    } else if (A11 > A22) {
        float s = sqrtf(1.f + A11 - A00 - A22) * 2.f;
        qy = 0.25f*s; float is = 1.f/s;
        qw = (A02 - A20)*is; qx = (A01 + A10)*is; qz = (A12 + A21)*is;
    } else {
        float s = sqrtf(1.f + A22 - A00 - A11) * 2.f;
        qz = 0.25f*s; float is = 1.f/s;
        qw = (A10 - A01)*is; qx = (A02 + A20)*is; qy = (A12 + A21)*is;
    }
    float inv = rsqrtf(qw*qw + qx*qx + qy*qy + qz*qz);
    return make_float4(qx*inv, qy*inv, qz*inv, qw*inv);
}

__device__ __forceinline__ void quat2mat(float4 q,
    float& R00, float& R01, float& R02,
    float& R10, float& R11, float& R12,
    float& R20, float& R21, float& R22) {
    float x=q.x, y=q.y, z=q.z, w=q.w;
    float xx=x*x, yy=y*y, zz=z*z;
    float xy=x*y, xz=x*z, yz=y*z, wx=w*x, wy=w*y, wz=w*z;
    R00 = 1.f-2.f*(yy+zz); R01 = 2.f*(xy-wz);     R02 = 2.f*(xz+wy);
    R10 = 2.f*(xy+wz);     R11 = 1.f-2.f*(xx+zz); R12 = 2.f*(yz-wx);
    R20 = 2.f*(xz-wy);     R21 = 2.f*(yz+wx);     R22 = 1.f-2.f*(xx+yy);
}

// 8 lanes per vertex; lane e handles edge e. S reduced via xor-shuffles.
__global__ __launch_bounds__(BLK) void rot_kernel(
    const float4* __restrict__ xyz4, const float4* __restrict__ rc,
    const int* __restrict__ nbr, const int* __restrict__ num,
    const int* __restrict__ acc, const float* __restrict__ wm,
    float4* __restrict__ quat, int n)
{
    int t = blockIdx.x * blockDim.x + threadIdx.x;
    int i = t >> 3, e = t & 7;
    if (i >= n) return;

    int e0 = acc[i];
    int cnt = num[i]; if (cnt > MAXK) cnt = MAXK;
    float4 xi = xyz4[i];
    float4 pi = rc[i];

    int j = i; float w = 0.f;
    if (e < cnt) { j = nbr[e0+e]; w = wm[e0+e]; }
    float4 xj = xyz4[j];
    float4 pj = rc[j];

    float we0 = w*(xi.x - xj.x), we1 = w*(xi.y - xj.y), we2 = w*(xi.z - xj.z);
    float ed0 = pi.x - pj.x, ed1 = pi.y - pj.y, ed2 = pi.z - pj.z;

    float S00 = we0*ed0, S01 = we0*ed1, S02 = we0*ed2;
    float S10 = we1*ed0, S11 = we1*ed1, S12 = we1*ed2;
    float S20 = we2*ed0, S21 = we2*ed1, S22 = we2*ed2;

#pragma unroll
    for (int m = 1; m < 8; m <<= 1) {
        S00 += __shfl_xor(S00, m); S01 += __shfl_xor(S01, m); S02 += __shfl_xor(S02, m);
        S10 += __shfl_xor(S10, m); S11 += __shfl_xor(S11, m); S12 += __shfl_xor(S12, m);
        S20 += __shfl_xor(S20, m); S21 += __shfl_xor(S21, m); S22 += __shfl_xor(S22, m);
    }

    float4 q = polar_quat(S00,S01,S02,S10,S11,S12,S20,S21,S22);
    if (e == 0) quat[i] = q;
}

__global__ __launch_bounds__(BLK) void grad_kernel(
    const float4* __restrict__ xyz4, const float4* __restrict__ rc,
    const int* __restrict__ nbr, const int* __restrict__ num,
    const int* __restrict__ acc, const float* __restrict__ wm,
    const float* __restrict__ arapW, const float4* __restrict__ quat,
    float4* __restrict__ mbuf, float4* __restrict__ vbuf,
    float4* __restrict__ rn, float* __restrict__ out,
    int n, int first, int last, float ib1, float ib2)
{
    int t = blockIdx.x * blockDim.x + threadIdx.x;
    int i = t >> 3, e = t & 7;
    if (i >= n) return;

    int e0 = acc[i];
    int cnt = num[i]; if (cnt > MAXK) cnt = MAXK;
    float4 xi = xyz4[i];
    float4 pi = rc[i];
    float4 qi = quat[i];

    int j = i; float w = 0.f;
    if (e < cnt) { j = nbr[e0+e]; w = wm[e0+e]; }
    float4 xj = xyz4[j];
    float4 pj = rc[j];
    float4 qj = quat[j];

    float Ri00,Ri01,Ri02,Ri10,Ri11,Ri12,Ri20,Ri21,Ri22;
    float Rj00,Rj01,Rj02,Rj10,Rj11,Rj12,Rj20,Rj21,Rj22;
    quat2mat(qi, Ri00,Ri01,Ri02,Ri10,Ri11,Ri12,Ri20,Ri21,Ri22);
    quat2mat(qj, Rj00,Rj01,Rj02,Rj10,Rj11,Rj12,Rj20,Rj21,Rj22);

    float we0 = w*(xi.x - xj.x), we1 = w*(xi.y - xj.y), we2 = w*(xi.z - xj.z);
    float ed0 = pi.x - pj.x, ed1 = pi.y - pj.y, ed2 = pi.z - pj.z;
    float tw = 2.f * w;

    float g0 = tw*ed0 - ((Ri00+Rj00)*we0 + (Ri01+Rj01)*we1 + (Ri02+Rj02)*we2);
    float g1 = tw*ed1 - ((Ri10+Rj10)*we0 + (Ri11+Rj11)*we1 + (Ri12+Rj12)*we2);
    float g2 = tw*ed2 - ((Ri20+Rj20)*we0 + (Ri21+Rj21)*we1 + (Ri22+Rj22)*we2);

#pragma unroll
    for (int m = 1; m < 8; m <<= 1) {
        g0 += __shfl_xor(g0, m);
        g1 += __shfl_xor(g1, m);
        g2 += __shfl_xor(g2, m);
    }

    if (e == 0) {
        float aw = arapW[0];
        g0 *= aw; g1 *= aw; g2 *= aw;

        float m0, m1, m2, v0, v1, v2;
        if (first) {
            m0 = 0.1f*g0; m1 = 0.1f*g1; m2 = 0.1f*g2;
            v0 = 0.001f*g0*g0; v1 = 0.001f*g1*g1; v2 = 0.001f*g2*g2;
        } else {
            float4 mo = mbuf[i], vo = vbuf[i];
            m0 = 0.9f*mo.x + 0.1f*g0;
            m1 = 0.9f*mo.y + 0.1f*g1;
            m2 = 0.9f*mo.z + 0.1f*g2;
            v0 = 0.999f*vo.x + 0.001f*g0*g0;
            v1 = 0.999f*vo.y + 0.001f*g1*g1;
            v2 = 0.999f*vo.z + 0.001f*g2*g2;
        }
        mbuf[i] = make_float4(m0, m1, m2, 0.f);
        vbuf[i] = make_float4(v0, v1, v2, 0.f);

        const float RATE = 0.01f, EPS = 1e-9f;
        float o0 = pi.x - RATE * ((m0*ib1) / (sqrtf(v0*ib2) + EPS));
        float o1 = pi.y - RATE * ((m1*ib1) / (sqrtf(v1*ib2) + EPS));
        float o2 = pi.z - RATE * ((m2*ib1) / (sqrtf(v2*ib2) + EPS));

        if (last) {
            out[3*(size_t)i+0] = o0;
            out[3*(size_t)i+1] = o1;
            out[3*(size_t)i+2] = o2;
        } else {
            rn[i] = make_float4(o0, o1, o2, 0.f);
        }
    }
}

extern "C" void kernel_launch(void* const* d_in, const int* in_sizes, int n_in,
                              void* d_out, int out_size, void* d_ws, size_t ws_size,
                              hipStream_t stream) {
    const float* xyz    = (const float*)d_in[0];
    const float* recon0 = (const float*)d_in[1];
    const int*   nbr    = (const int*)d_in[2];
    const int*   num    = (const int*)d_in[3];
    const int*   acc    = (const int*)d_in[4];
    const float* wm     = (const float*)d_in[5];
    const float* aw     = (const float*)d_in[6];

    int n = in_sizes[0] / 3;
    float* out = (float*)d_out;

    float4* xyz4  = (float4*)d_ws;                 // n
    float4* quat  = xyz4  + (size_t)n;             // n
    float4* rbufA = quat  + (size_t)n;             // n
    float4* rbufB = rbufA + (size_t)n;             // n
    float4* mbuf  = rbufB + (size_t)n;             // n
    float4* vbuf  = mbuf  + (size_t)n;             // n

    int gridV = (n + BLK - 1) / BLK;               // 1 thread/vertex
    int gridE = ((size_t)n * 8 + BLK - 1) / BLK;   // 8 lanes/vertex

    prep_kernel<<<gridV, BLK, 0, stream>>>(xyz, recon0, xyz4, rbufA, n);

    const float4* rc = rbufA;
    float4*       rn = rbufB;
    for (int step = 1; step <= NSTEP; ++step) {
        rot_kernel<<<gridE, BLK, 0, stream>>>(xyz4, rc, nbr, num, acc, wm,
                                              quat, n);
        float ib1 = 1.0f / (1.0f - powf(0.9f,   (float)step));
        float ib2 = 1.0f / (1.0f - powf(0.999f, (float)step));
        grad_kernel<<<gridE, BLK, 0, stream>>>(xyz4, rc, nbr, num, acc, wm,
                                               aw, quat, mbuf, vbuf, rn, out,
                                               n, step == 1 ? 1 : 0,
                                               step == NSTEP ? 1 : 0, ib1, ib2);
        const float4* tmp = rc; rc = rn; rn = (float4*)tmp;
    }
}

// Round 6
// 319.180 us; speedup vs baseline: 1.6642x; 1.4816x over previous
//
#include <hip/hip_runtime.h>
#include <math.h>

// ARAP projection, 8 Adam steps. Per step, 3 dispatches:
//  1) s_kernel    (8 lanes/vertex): gather edges, reduce S via shfl_xor,
//                 write S rows (3x float4 SoA).      [memory phase]
//  2) polar_kernel(1 thread/vertex): Newton polar + det<0 fix -> quat.
//                 Full lane utilization (R5 wasted 8x VALU here).
//  3) grad_kernel (8 lanes/vertex): gather quats/recon, reduce grad, Adam.
// Rotations stored as unit quaternions (16B gather).

#define BLK 256
#define MAXK 8
#define NSTEP 8

__global__ void prep_kernel(const float* __restrict__ xyz,
                            const float* __restrict__ recon0,
                            float4* __restrict__ xyz4,
                            float4* __restrict__ rbufA, int n) {
    int i = blockIdx.x * blockDim.x + threadIdx.x;
    if (i < n) {
        xyz4[i]  = make_float4(xyz[3*i], xyz[3*i+1], xyz[3*i+2], 0.f);
        rbufA[i] = make_float4(recon0[3*i], recon0[3*i+1], recon0[3*i+2], 0.f);
    }
}

// ---- step 1: S accumulation, edge-parallel --------------------------------
__global__ __launch_bounds__(BLK) void s_kernel(
    const float4* __restrict__ xyz4, const float4* __restrict__ rc,
    const int* __restrict__ nbr, const int* __restrict__ num,
    const int* __restrict__ acc, const float* __restrict__ wm,
    float4* __restrict__ Sr0, float4* __restrict__ Sr1,
    float4* __restrict__ Sr2, int n)
{
    int t = blockIdx.x * blockDim.x + threadIdx.x;
    int i = t >> 3, e = t & 7;
    if (i >= n) return;

    int e0 = acc[i];
    int cnt = num[i]; if (cnt > MAXK) cnt = MAXK;
    float4 xi = xyz4[i];
    float4 pi = rc[i];

    int j = i; float w = 0.f;
    if (e < cnt) { j = nbr[e0+e]; w = wm[e0+e]; }
    float4 xj = xyz4[j];
    float4 pj = rc[j];

    float we0 = w*(xi.x - xj.x), we1 = w*(xi.y - xj.y), we2 = w*(xi.z - xj.z);
    float ed0 = pi.x - pj.x, ed1 = pi.y - pj.y, ed2 = pi.z - pj.z;

    float S00 = we0*ed0, S01 = we0*ed1, S02 = we0*ed2;
    float S10 = we1*ed0, S11 = we1*ed1, S12 = we1*ed2;
    float S20 = we2*ed0, S21 = we2*ed1, S22 = we2*ed2;

#pragma unroll
    for (int m = 1; m < 8; m <<= 1) {
        S00 += __shfl_xor(S00, m); S01 += __shfl_xor(S01, m); S02 += __shfl_xor(S02, m);
        S10 += __shfl_xor(S10, m); S11 += __shfl_xor(S11, m); S12 += __shfl_xor(S12, m);
        S20 += __shfl_xor(S20, m); S21 += __shfl_xor(S21, m); S22 += __shfl_xor(S22, m);
    }

    // lanes 0,1,2 of each 8-lane group each write one row
    if (e == 0) Sr0[i] = make_float4(S00, S01, S02, 0.f);
    if (e == 1) Sr1[i] = make_float4(S10, S11, S12, 0.f);
    if (e == 2) Sr2[i] = make_float4(S20, S21, S22, 0.f);
}

// ---- step 2: polar decomposition, vertex-parallel (full lane util) --------
__global__ __launch_bounds__(BLK) void polar_kernel(
    const float4* __restrict__ Sr0, const float4* __restrict__ Sr1,
    const float4* __restrict__ Sr2, float4* __restrict__ quat, int n)
{
    int i = blockIdx.x * blockDim.x + threadIdx.x;
    if (i >= n) return;

    float4 r0 = Sr0[i], r1 = Sr1[i], r2 = Sr2[i];
    float S00 = r0.x, S01 = r0.y, S02 = r0.z;
    float S10 = r1.x, S11 = r1.y, S12 = r1.z;
    float S20 = r2.x, S21 = r2.y, S22 = r2.z;

    float detS = S00*(S11*S22 - S12*S21)
               - S01*(S10*S22 - S12*S20)
               + S02*(S10*S21 - S11*S20);

    // A = S^T ; scaled Newton polar -> Q = V U^T, det(Q)=sign(det S)
    float A00 = S00, A01 = S10, A02 = S20;
    float A10 = S01, A11 = S11, A12 = S21;
    float A20 = S02, A21 = S12, A22 = S22;

    float fS = A00*A00+A01*A01+A02*A02+A10*A10+A11*A11+A12*A12
             + A20*A20+A21*A21+A22*A22;
    if (fS < 1e-24f) {
        A00=1.f; A01=0.f; A02=0.f;
        A10=0.f; A11=1.f; A12=0.f;
        A20=0.f; A21=0.f; A22=1.f;
    } else {
#pragma unroll
        for (int it = 0; it < 10; ++it) {
            float C00 = A11*A22 - A12*A21;
            float C01 = A12*A20 - A10*A22;
            float C02 = A10*A21 - A11*A20;
            float C10 = A02*A21 - A01*A22;
            float C11 = A00*A22 - A02*A20;
            float C12 = A01*A20 - A00*A21;
            float C20 = A01*A12 - A02*A11;
            float C21 = A02*A10 - A00*A12;
            float C22 = A00*A11 - A01*A10;
            float det = A00*C00 + A01*C01 + A02*C02;
            float ad = fmaxf(fabsf(det), 1e-30f);
            det = (det < 0.f) ? -ad : ad;
            float fA = A00*A00+A01*A01+A02*A02+A10*A10+A11*A11
                     + A12*A12+A20*A20+A21*A21+A22*A22;
            float fC = C00*C00+C01*C01+C02*C02+C10*C10+C11*C11
                     + C12*C12+C20*C20+C21*C21+C22*C22;
            float g = sqrtf(sqrtf(fC / fmaxf(ad*ad*fA, 1e-38f)));
            float s0 = 0.5f * g;
            float s1 = 0.5f / (g * det);
            A00 = s0*A00 + s1*C00; A01 = s0*A01 + s1*C01; A02 = s0*A02 + s1*C02;
            A10 = s0*A10 + s1*C10; A11 = s0*A11 + s1*C11; A12 = s0*A12 + s1*C12;
            A20 = s0*A20 + s1*C20; A21 = s0*A21 + s1*C21; A22 = s0*A22 + s1*C22;
        }

        if (detS < 0.f) {
            // R = Q (I - 2 u3 u3^T), u3 = min-eigvec of H = Q^T S^T
            float H00 = A00*S00 + A10*S01 + A20*S02;
            float H01 = A00*S10 + A10*S11 + A20*S12;
            float H02 = A00*S20 + A10*S21 + A20*S22;
            float H10 = A01*S00 + A11*S01 + A21*S02;
            float H11 = A01*S10 + A11*S11 + A21*S12;
            float H12 = A01*S20 + A11*S21 + A21*S22;
            float H20 = A02*S00 + A12*S01 + A22*S02;
            float H21 = A02*S10 + A12*S11 + A22*S12;
            float H22 = A02*S20 + A12*S21 + A22*S22;
            float h01 = 0.5f*(H01 + H10);
            float h02 = 0.5f*(H02 + H20);
            float h12 = 0.5f*(H12 + H21);

            float q  = (H00 + H11 + H22) * (1.f/3.f);
            float p1 = h01*h01 + h02*h02 + h12*h12;
            float a00 = H00 - q, a11 = H11 - q, a22 = H22 - q;
            float p2 = a00*a00 + a11*a11 + a22*a22 + 2.f*p1;
            float p  = sqrtf(fmaxf(p2 * (1.f/6.f), 1e-30f));
            float ip = 1.f / p;
            float b00 = a00*ip, b01 = h01*ip, b02 = h02*ip;
            float b11 = a11*ip, b12 = h12*ip, b22 = a22*ip;
            float detB = b00*(b11*b22 - b12*b12)
                       - b01*(b01*b22 - b12*b02)
                       + b02*(b01*b12 - b11*b02);
            float r   = fminf(1.f, fmaxf(-1.f, 0.5f*detB));
            float phi = acosf(r) * (1.f/3.f);
            float l1 = q + 2.f*p*cosf(phi);
            float l3 = q + 2.f*p*cosf(phi + 2.0943951023931953f);
            float l2 = 3.f*q - l1 - l3;

            float m100 = H00-l1, m111 = H11-l1, m122 = H22-l1;
            float m200 = H00-l2, m211 = H11-l2, m222 = H22-l2;
            float P00 = m100*m200 + h01*h01 + h02*h02;
            float P10 = h01*m200 + m111*h01 + h12*h02;
            float P20 = h02*m200 + h12*h01 + m122*h02;
            float P01 = m100*h01 + h01*m211 + h02*h12;
            float P11 = h01*h01 + m111*m211 + h12*h12;
            float P21 = h02*h01 + h12*m211 + m122*h12;
            float P02 = m100*h02 + h01*h12 + h02*m222;
            float P12 = h01*h02 + m111*h12 + h12*m222;
            float P22 = h02*h02 + h12*h12 + m122*m222;

            float n0 = P00*P00 + P10*P10 + P20*P20;
            float n1 = P01*P01 + P11*P11 + P21*P21;
            float n2 = P02*P02 + P12*P12 + P22*P22;
            float u0, u1, u2, nn;
            if (n0 >= n1 && n0 >= n2) { u0=P00; u1=P10; u2=P20; nn=n0; }
            else if (n1 >= n2)        { u0=P01; u1=P11; u2=P21; nn=n1; }
            else                      { u0=P02; u1=P12; u2=P22; nn=n2; }
            if (nn > 1e-30f) {
                float inv = rsqrtf(nn);
                u0 *= inv; u1 *= inv; u2 *= inv;
                float Qu0 = A00*u0 + A01*u1 + A02*u2;
                float Qu1 = A10*u0 + A11*u1 + A12*u2;
                float Qu2 = A20*u0 + A21*u1 + A22*u2;
                A00 -= 2.f*Qu0*u0; A01 -= 2.f*Qu0*u1; A02 -= 2.f*Qu0*u2;
                A10 -= 2.f*Qu1*u0; A11 -= 2.f*Qu1*u1; A12 -= 2.f*Qu1*u2;
                A20 -= 2.f*Qu2*u0; A21 -= 2.f*Qu2*u1; A22 -= 2.f*Qu2*u2;
            }
        }
    }

    // rotation matrix -> quaternion (Shepperd)
    float qw, qx, qy, qz;
    float tr = A00 + A11 + A22;
    if (tr > 0.f) {
        float s = sqrtf(tr + 1.f) * 2.f;
        qw = 0.25f*s; float is = 1.f/s;
        qx = (A21 - A12)*is; qy = (A02 - A20)*is; qz = (A10 - A01)*is;
    } else if (A00 > A11 && A00 > A22) {
        float s = sqrtf(1.f + A00 - A11 - A22) * 2.f;
        qx = 0.25f*s; float is = 1.f/s;
        qw = (A21 - A12)*is; qy = (A01 + A10)*is; qz = (A02 + A20)*is;
    } else if (A11 > A22) {
        float s = sqrtf(1.f + A11 - A00 - A22) * 2.f;
        qy = 0.25f*s; float is = 1.f/s;
        qw = (A02 - A20)*is; qx = (A01 + A10)*is; qz = (A12 + A21)*is;
    } else {
        float s = sqrtf(1.f + A22 - A00 - A11) * 2.f;
        qz = 0.25f*s; float is = 1.f/s;
        qw = (A10 - A01)*is; qx = (A02 + A20)*is; qy = (A12 + A21)*is;
    }
    float inv = rsqrtf(qw*qw + qx*qx + qy*qy + qz*qz);
    quat[i] = make_float4(qx*inv, qy*inv, qz*inv, qw*inv);
}

__device__ __forceinline__ void quat2mat(float4 q,
    float& R00, float& R01, float& R02,
    float& R10, float& R11, float& R12,
    float& R20, float& R21, float& R22) {
    float x=q.x, y=q.y, z=q.z, w=q.w;
    float xx=x*x, yy=y*y, zz=z*z;
    float xy=x*y, xz=x*z, yz=y*z, wx=w*x, wy=w*y, wz=w*z;
    R00 = 1.f-2.f*(yy+zz); R01 = 2.f*(xy-wz);     R02 = 2.f*(xz+wy);
    R10 = 2.f*(xy+wz);     R11 = 1.f-2.f*(xx+zz); R12 = 2.f*(yz-wx);
    R20 = 2.f*(xz-wy);     R21 = 2.f*(yz+wx);     R22 = 1.f-2.f*(xx+yy);
}

// ---- step 3: gradient + Adam, edge-parallel -------------------------------
__global__ __launch_bounds__(BLK) void grad_kernel(
    const float4* __restrict__ xyz4, const float4* __restrict__ rc,
    const int* __restrict__ nbr, const int* __restrict__ num,
    const int* __restrict__ acc, const float* __restrict__ wm,
    const float* __restrict__ arapW, const float4* __restrict__ quat,
    float4* __restrict__ mbuf, float4* __restrict__ vbuf,
    float4* __restrict__ rn, float* __restrict__ out,
    int n, int first, int last, float ib1, float ib2)
{
    int t = blockIdx.x * blockDim.x + threadIdx.x;
    int i = t >> 3, e = t & 7;
    if (i >= n) return;

    int e0 = acc[i];
    int cnt = num[i]; if (cnt > MAXK) cnt = MAXK;
    float4 xi = xyz4[i];
    float4 pi = rc[i];
    float4 qi = quat[i];

    int j = i; float w = 0.f;
    if (e < cnt) { j = nbr[e0+e]; w = wm[e0+e]; }
    float4 xj = xyz4[j];
    float4 pj = rc[j];
    float4 qj = quat[j];

    float Ri00,Ri01,Ri02,Ri10,Ri11,Ri12,Ri20,Ri21,Ri22;
    float Rj00,Rj01,Rj02,Rj10,Rj11,Rj12,Rj20,Rj21,Rj22;
    quat2mat(qi, Ri00,Ri01,Ri02,Ri10,Ri11,Ri12,Ri20,Ri21,Ri22);
    quat2mat(qj, Rj00,Rj01,Rj02,Rj10,Rj11,Rj12,Rj20,Rj21,Rj22);

    float we0 = w*(xi.x - xj.x), we1 = w*(xi.y - xj.y), we2 = w*(xi.z - xj.z);
    float ed0 = pi.x - pj.x, ed1 = pi.y - pj.y, ed2 = pi.z - pj.z;
    float tw = 2.f * w;

    float g0 = tw*ed0 - ((Ri00+Rj00)*we0 + (Ri01+Rj01)*we1 + (Ri02+Rj02)*we2);
    float g1 = tw*ed1 - ((Ri10+Rj10)*we0 + (Ri11+Rj11)*we1 + (Ri12+Rj12)*we2);
    float g2 = tw*ed2 - ((Ri20+Rj20)*we0 + (Ri21+Rj21)*we1 + (Ri22+Rj22)*we2);

#pragma unroll
    for (int m = 1; m < 8; m <<= 1) {
        g0 += __shfl_xor(g0, m);
        g1 += __shfl_xor(g1, m);
        g2 += __shfl_xor(g2, m);
    }

    if (e == 0) {
        float aw = arapW[0];
        g0 *= aw; g1 *= aw; g2 *= aw;

        float m0, m1, m2, v0, v1, v2;
        if (first) {
            m0 = 0.1f*g0; m1 = 0.1f*g1; m2 = 0.1f*g2;
            v0 = 0.001f*g0*g0; v1 = 0.001f*g1*g1; v2 = 0.001f*g2*g2;
        } else {
            float4 mo = mbuf[i], vo = vbuf[i];
            m0 = 0.9f*mo.x + 0.1f*g0;
            m1 = 0.9f*mo.y + 0.1f*g1;
            m2 = 0.9f*mo.z + 0.1f*g2;
            v0 = 0.999f*vo.x + 0.001f*g0*g0;
            v1 = 0.999f*vo.y + 0.001f*g1*g1;
            v2 = 0.999f*vo.z + 0.001f*g2*g2;
        }
        mbuf[i] = make_float4(m0, m1, m2, 0.f);
        vbuf[i] = make_float4(v0, v1, v2, 0.f);

        const float RATE = 0.01f, EPS = 1e-9f;
        float o0 = pi.x - RATE * ((m0*ib1) / (sqrtf(v0*ib2) + EPS));
        float o1 = pi.y - RATE * ((m1*ib1) / (sqrtf(v1*ib2) + EPS));
        float o2 = pi.z - RATE * ((m2*ib1) / (sqrtf(v2*ib2) + EPS));

        if (last) {
            out[3*(size_t)i+0] = o0;
            out[3*(size_t)i+1] = o1;
            out[3*(size_t)i+2] = o2;
        } else {
            rn[i] = make_float4(o0, o1, o2, 0.f);
        }
    }
}

extern "C" void kernel_launch(void* const* d_in, const int* in_sizes, int n_in,
                              void* d_out, int out_size, void* d_ws, size_t ws_size,
                              hipStream_t stream) {
    const float* xyz    = (const float*)d_in[0];
    const float* recon0 = (const float*)d_in[1];
    const int*   nbr    = (const int*)d_in[2];
    const int*   num    = (const int*)d_in[3];
    const int*   acc    = (const int*)d_in[4];
    const float* wm     = (const float*)d_in[5];
    const float* aw     = (const float*)d_in[6];

    int n = in_sizes[0] / 3;
    float* out = (float*)d_out;

    float4* xyz4  = (float4*)d_ws;                 // n
    float4* quat  = xyz4  + (size_t)n;             // n
    float4* rbufA = quat  + (size_t)n;             // n
    float4* rbufB = rbufA + (size_t)n;             // n
    float4* mbuf  = rbufB + (size_t)n;             // n
    float4* vbuf  = mbuf  + (size_t)n;             // n
    float4* Sr0   = vbuf  + (size_t)n;             // n
    float4* Sr1   = Sr0   + (size_t)n;             // n
    float4* Sr2   = Sr1   + (size_t)n;             // n

    int gridV = (n + BLK - 1) / BLK;               // 1 thread/vertex
    int gridE = ((size_t)n * 8 + BLK - 1) / BLK;   // 8 lanes/vertex

    prep_kernel<<<gridV, BLK, 0, stream>>>(xyz, recon0, xyz4, rbufA, n);

    const float4* rc = rbufA;
    float4*       rn = rbufB;
    for (int step = 1; step <= NSTEP; ++step) {
        s_kernel<<<gridE, BLK, 0, stream>>>(xyz4, rc, nbr, num, acc, wm,
                                            Sr0, Sr1, Sr2, n);
        polar_kernel<<<gridV, BLK, 0, stream>>>(Sr0, Sr1, Sr2, quat, n);
        float ib1 = 1.0f / (1.0f - powf(0.9f,   (float)step));
        float ib2 = 1.0f / (1.0f - powf(0.999f, (float)step));
        grad_kernel<<<gridE, BLK, 0, stream>>>(xyz4, rc, nbr, num, acc, wm,
                                               aw, quat, mbuf, vbuf, rn, out,
                                               n, step == 1 ? 1 : 0,
                                               step == NSTEP ? 1 : 0, ib1, ib2);
        const float4* tmp = rc; rc = rn; rn = (float4*)tmp;
    }
}